// Round 1
// baseline (729.532 us; speedup 1.0000x reference)
//
#include <hip/hip_runtime.h>
#include <cstddef>

// Shapes (fixed): B=1, S=256, H=8, D=64
//   c,b,a: [256, 8, 64]   (r/q/p, n, k/j/i)  row-major
//   W:     [8, 64, 64, 64] (n, i, j, k)      row-major
//   out:   [8, 256, 256, 256] (n, p, q, r)   row-major, fp32, 512 MiB
//
// Pipeline (ws scratch, fp32):
//   bs[q,j]        = sum_n b[q,n,j]                          (16384 floats)
//   T1[(i*256+r),j]= sum_{n,k} c[r,n,k] * W[n,i,j,k]         (1048576 floats)
//   T2[q,i,r]      = sum_j  bs[q,j] * T1[(i,r),j]            (4194304 floats)
//   out[n,p,q,r]   = sum_i  a[p,n,i] * T2[q,i,r]

#define LDS_STRIDE 68  // 16B-aligned rows (68*4B), <=2-way bank aliasing

__global__ __launch_bounds__(256) void bsum_kernel(const float* __restrict__ b,
                                                   float* __restrict__ bs) {
    int t = blockIdx.x * 256 + threadIdx.x;  // 0..16383
    int q = t >> 6, j = t & 63;
    float s = 0.f;
#pragma unroll
    for (int n = 0; n < 8; ++n) s += b[q * 512 + n * 64 + j];
    bs[t] = s;
}

// T1[(i*256+r)*64 + j] = sum_{nk} c[r*512 + nk] * W[n*262144 + i*4096 + j*64 + k]
// GEMM per i: M=256(r) x N=64(j) x K=512(nk). Block = one (i, r-tile-of-64).
__global__ __launch_bounds__(256) void step1_kernel(const float* __restrict__ c,
                                                    const float* __restrict__ W,
                                                    float* __restrict__ T1) {
    __shared__ alignas(16) float As[16 * LDS_STRIDE];
    __shared__ alignas(16) float Bs[16 * LDS_STRIDE];
    const int i  = blockIdx.x;       // 0..63
    const int r0 = blockIdx.y * 64;  // 0..3 * 64
    const int t  = threadIdx.x;
    const int tx = t & 15, ty = t >> 4;
    float acc[4][4] = {};

    for (int kk0 = 0; kk0 < 512; kk0 += 16) {
        // stage A: c rows r0..r0+63, cols kk0..kk0+15  -> As[kc][row]
        {
            const int kc = t & 15, rb = t >> 4;
#pragma unroll
            for (int ii = 0; ii < 4; ++ii) {
                const int row = rb + ii * 16;
                As[kc * LDS_STRIDE + row] = c[(r0 + row) * 512 + kk0 + kc];
            }
        }
        // stage B: W[nw, i, j, k0+kc] -> Bs[kc][j]   (kk0 = nw*64 + k0, k0 in {0,16,32,48})
        {
            const int nw = kk0 >> 6, k0 = kk0 & 63;
            const float* wbase = W + nw * 262144 + i * 4096 + k0;
            const int kc = t & 15, jb = t >> 4;
#pragma unroll
            for (int ii = 0; ii < 4; ++ii) {
                const int j = jb + ii * 16;
                Bs[kc * LDS_STRIDE + j] = wbase[j * 64 + kc];
            }
        }
        __syncthreads();
#pragma unroll
        for (int k = 0; k < 16; ++k) {
            const float4 av = *(const float4*)&As[k * LDS_STRIDE + ty * 4];
            const float4 bv = *(const float4*)&Bs[k * LDS_STRIDE + tx * 4];
            const float aa[4] = {av.x, av.y, av.z, av.w};
            const float bb[4] = {bv.x, bv.y, bv.z, bv.w};
#pragma unroll
            for (int u = 0; u < 4; ++u)
#pragma unroll
                for (int v = 0; v < 4; ++v) acc[u][v] += aa[u] * bb[v];
        }
        __syncthreads();
    }
#pragma unroll
    for (int u = 0; u < 4; ++u) {
        const int r = r0 + ty * 4 + u;
        float4 v4 = make_float4(acc[u][0], acc[u][1], acc[u][2], acc[u][3]);
        *(float4*)&T1[(i * 256 + r) * 64 + tx * 4] = v4;
    }
}

// T2[q*16384 + m] = sum_j bs[q*64+j] * T1[m*64 + j],  m = i*256+r
// NT GEMM: M=256(q) x N=16384(m) x K=64(j)
__global__ __launch_bounds__(256) void step2_kernel(const float* __restrict__ bs,
                                                    const float* __restrict__ T1,
                                                    float* __restrict__ T2) {
    __shared__ alignas(16) float As[16 * LDS_STRIDE];
    __shared__ alignas(16) float Bs[16 * LDS_STRIDE];
    const int m0 = blockIdx.x * 64;  // 0..255 * 64
    const int q0 = blockIdx.y * 64;  // 0..3   * 64
    const int t  = threadIdx.x;
    const int tx = t & 15, ty = t >> 4;
    float acc[4][4] = {};

    for (int kk0 = 0; kk0 < 64; kk0 += 16) {
        const int kc = t & 15, rb = t >> 4;
#pragma unroll
        for (int ii = 0; ii < 4; ++ii) {
            const int row = rb + ii * 16;
            As[kc * LDS_STRIDE + row] = bs[(q0 + row) * 64 + kk0 + kc];
        }
#pragma unroll
        for (int ii = 0; ii < 4; ++ii) {
            const int row = rb + ii * 16;
            Bs[kc * LDS_STRIDE + row] = T1[(m0 + row) * 64 + kk0 + kc];
        }
        __syncthreads();
#pragma unroll
        for (int k = 0; k < 16; ++k) {
            const float4 av = *(const float4*)&As[k * LDS_STRIDE + ty * 4];
            const float4 bv = *(const float4*)&Bs[k * LDS_STRIDE + tx * 4];
            const float aa[4] = {av.x, av.y, av.z, av.w};
            const float bb[4] = {bv.x, bv.y, bv.z, bv.w};
#pragma unroll
            for (int u = 0; u < 4; ++u)
#pragma unroll
                for (int v = 0; v < 4; ++v) acc[u][v] += aa[u] * bb[v];
        }
        __syncthreads();
    }
#pragma unroll
    for (int u = 0; u < 4; ++u) {
        const int q = q0 + ty * 4 + u;
        float4 v4 = make_float4(acc[u][0], acc[u][1], acc[u][2], acc[u][3]);
        *(float4*)&T2[q * 16384 + m0 + tx * 4] = v4;
    }
}

// out[n*2^24 + p*65536 + q*256 + r] = sum_i a[p*512 + n*64 + i] * T2[q*16384 + i*256 + r]
// NN GEMM per (n,q): M=256(p) x N=256(r) x K=64(i)
__global__ __launch_bounds__(256) void step3_kernel(const float* __restrict__ a,
                                                    const float* __restrict__ T2,
                                                    float* __restrict__ out) {
    __shared__ alignas(16) float As[16 * LDS_STRIDE];
    __shared__ alignas(16) float Bs[16 * LDS_STRIDE];
    const int nq = blockIdx.y;
    const int q = nq & 255, n = nq >> 8;
    const int p0 = (blockIdx.x >> 2) * 64;
    const int r0 = (blockIdx.x & 3) * 64;
    const int t  = threadIdx.x;
    const int tx = t & 15, ty = t >> 4;
    float acc[4][4] = {};

    for (int i0 = 0; i0 < 64; i0 += 16) {
        // A: a[(p0+prow), n, i0+kc] -> As[kc][prow]
        {
            const int kc = t & 15, rb = t >> 4;
#pragma unroll
            for (int ii = 0; ii < 4; ++ii) {
                const int prow = rb + ii * 16;
                As[kc * LDS_STRIDE + prow] = a[(p0 + prow) * 512 + n * 64 + i0 + kc];
            }
        }
        // B: T2[q, i0+ic, r0+rr] -> Bs[ic][rr]  (already k-major, coalesced)
        {
            const int ic4 = t >> 6, rr = t & 63;
#pragma unroll
            for (int ii = 0; ii < 4; ++ii) {
                const int ic = ic4 + ii * 4;
                Bs[ic * LDS_STRIDE + rr] = T2[q * 16384 + (i0 + ic) * 256 + r0 + rr];
            }
        }
        __syncthreads();
#pragma unroll
        for (int k = 0; k < 16; ++k) {
            const float4 av = *(const float4*)&As[k * LDS_STRIDE + ty * 4];
            const float4 bv = *(const float4*)&Bs[k * LDS_STRIDE + tx * 4];
            const float aa[4] = {av.x, av.y, av.z, av.w};
            const float bb[4] = {bv.x, bv.y, bv.z, bv.w};
#pragma unroll
            for (int u = 0; u < 4; ++u)
#pragma unroll
                for (int v = 0; v < 4; ++v) acc[u][v] += aa[u] * bb[v];
        }
        __syncthreads();
    }
    const size_t obase = (size_t)n * 16777216 + (size_t)q * 256;
#pragma unroll
    for (int u = 0; u < 4; ++u) {
        const int p = p0 + ty * 4 + u;
        float4 v4 = make_float4(acc[u][0], acc[u][1], acc[u][2], acc[u][3]);
        *(float4*)&out[obase + (size_t)p * 65536 + r0 + tx * 4] = v4;
    }
}

extern "C" void kernel_launch(void* const* d_in, const int* in_sizes, int n_in,
                              void* d_out, int out_size, void* d_ws, size_t ws_size,
                              hipStream_t stream) {
    const float* c = (const float*)d_in[0];
    const float* b = (const float*)d_in[1];
    const float* a = (const float*)d_in[2];
    const float* W = (const float*)d_in[3];
    float* out = (float*)d_out;

    // workspace layout (floats): bs[16384] | T1[1048576] | T2[4194304]  (~20.1 MiB)
    float* bs = (float*)d_ws;
    float* T1 = bs + 16384;
    float* T2 = T1 + 1048576;

    hipLaunchKernelGGL(bsum_kernel, dim3(64), dim3(256), 0, stream, b, bs);
    hipLaunchKernelGGL(step1_kernel, dim3(64, 4), dim3(256), 0, stream, c, W, T1);
    hipLaunchKernelGGL(step2_kernel, dim3(256, 4), dim3(256), 0, stream, bs, T1, T2);
    hipLaunchKernelGGL(step3_kernel, dim3(16, 2048), dim3(256), 0, stream, a, T2, out);
}